// Round 7
// baseline (159.536 us; speedup 1.0000x reference)
//
#include <hip/hip_runtime.h>
#include <hip/hip_bf16.h>

// Shapes: b=2,t=8,l=1024,c=256,h=8,d=32 -> NTOK=16384, BTH=128
// Inputs/outputs: float32. ws intermediates: _Float16.
// ws layout (f16): qn | kn | vt (each 4194304 elems, 24MB) | w16 (4x65536,
//   512KB, k-major tiled [kk][och][32] for Wq,Wk,Wv,Wm).
//   xa ALIASES qn: attn reads its q-rows at kernel start and writes its
//   output to exactly those rows at the end; row ranges are disjoint across
//   blocks, so the alias is race-free. This keeps w16 (incl. Wm) alive for
//   out_proj.
//   vt TRANSPOSED: [bth][32][l] with the k (column) index bit-permuted
//   (bits 2<->3 swapped within each 16-block) so a plain f16x8 load yields
//   the PV A-fragment matching P's register order after swapped QK^T.
// qn is pre-scaled by log2(e)/sqrt(32) so attn uses exp2 directly.
//
// Round 7: (a) attn single-barrier-per-tile: the ds_write of tile t+1 moves
// to the TOP of iteration t (its old readers -- compute(t-1) -- are already
// fenced by the end-of-iteration barrier of t-1), halving barriers 32->16.
// (b) proj 64-token blocks: W A-frag line traffic (the dominant per-wave
// line cost, 32x 1KB dense loads) amortizes over 2x tokens; LDS 41KB,
// grid (256,3) = 3 blocks/CU exactly resident.

#define NTOK  16384
#define CDIM  256
#define LSEQ  1024
#define HEADS 8
#define DHEAD 32

typedef _Float16 f16;
typedef __attribute__((ext_vector_type(2))) _Float16 f16x2;
typedef __attribute__((ext_vector_type(4))) _Float16 f16x4;
typedef __attribute__((ext_vector_type(8))) _Float16 f16x8;
typedef __attribute__((ext_vector_type(4))) float f32x4;
typedef __attribute__((ext_vector_type(16))) float f32x16;

#define QSCALE (0.17677669529663687f * 1.4426950408889634f)  // 1/sqrt(32)*log2e

__device__ __forceinline__ f16x2 pkcvt(float a, float b) {
  auto r = __builtin_amdgcn_cvt_pkrtz(a, b);  // v_cvt_pkrtz_f16_f32
  union { decltype(r) in; f16x2 out; } u;
  u.in = r;
  return u.out;
}

__device__ __forceinline__ f16x4 pack4(float4 a) {
  union { f16x4 v; f16x2 h[2]; } u;
  u.h[0] = pkcvt(a.x, a.y);
  u.h[1] = pkcvt(a.z, a.w);
  return u.v;
}

// ---------------------------------------------------------------------------
// Kernel 0: convert Wq|Wk|Wv|Wm (each 256x256 f32) to f16 in k-major tiles:
// dst[m*65536 + kk*8192 + och*32 + (ch&31)] — so a wave's MFMA A-fragment
// load (16 och rows x 32 ch) is one contiguous 1KB block.
// ---------------------------------------------------------------------------
__global__ __launch_bounds__(256)
void cvt_w_kernel(const float* __restrict__ Wq, const float* __restrict__ Wk,
                  const float* __restrict__ Wv, const float* __restrict__ Wm,
                  f16* __restrict__ dst) {
  const int m = blockIdx.x >> 6;  // matrix index (4 x 64 blocks)
  const float* src = (m == 0) ? Wq : (m == 1) ? Wk : (m == 2) ? Wv : Wm;
  const int base = (blockIdx.x & 63) * 1024 + threadIdx.x * 4;  // och*256+ch
  const int och = base >> 8, ch = base & 255;
  float4 a = *(const float4*)(src + base);
  *(f16x4*)(dst + m * 65536 + (ch >> 5) * 8192 + och * 32 + (ch & 31)) =
      pack4(a);
}

// ---------------------------------------------------------------------------
// Kernel 1: fused Q/K/V projection + bias + per-head L2-norm via MFMA.
// Grid (256, 3): blockIdx.y selects tensor; 64 tokens/block, 4 waves,
// wave w computes och 64w..64w+63 (heads 2w,2w+1) x 64 tokens.
// x tile staged to LDS [kk][tok][40] (dense 1KB token-row reads, pkcvt on
// the fly); A-frags from k-major w16 (dense 1KB). No strided hot loads.
// C-layout: col=l16 -> token, row=quad*4+r -> och.
// V store: transposed [32][LSEQ] with column bits 2<->3 swapped (see header).
// ---------------------------------------------------------------------------
#define PKKB 2568  // (64 tok * 40 + 8 pad) f16 per kk block

__global__ __launch_bounds__(256, 2)
void proj_mfma_kernel(const float* __restrict__ xq, const float* __restrict__ xk,
                      const float* __restrict__ xv, const f16* __restrict__ w16,
                      const float* __restrict__ bq, const float* __restrict__ bk,
                      const float* __restrict__ bv,
                      f16* __restrict__ qn, f16* __restrict__ kn,
                      f16* __restrict__ vt) {
  __shared__ f16 xl[8 * PKKB];  // 41088 B
  const int which = blockIdx.y;
  const float* x    = (which == 0) ? xq : (which == 1) ? xk : xv;
  const float* bias = (which == 0) ? bq : (which == 1) ? bk : bv;
  const f16* W      = w16 + which * 65536;
  f16* out          = (which == 0) ? qn : (which == 1) ? kn : vt;
  const float scale = (which == 0) ? QSCALE : 1.0f;
  const bool transposed = (which == 2);

  const int tid = threadIdx.x;
  const int wave = tid >> 6, lane = tid & 63;
  const int quad = lane >> 4, l16 = lane & 15;
  const int tokbase = blockIdx.x * 64;
  const int wbase = wave * 64;

  // ---- stage x tile: 16 rounds, each wave reads ONE full token row (1KB
  // dense), converts, writes f16x4 to LDS.
  {
    const int c16 = lane;  // 64 16B-chunks per token
#pragma unroll
    for (int r = 0; r < 16; ++r) {
      const int tok = r * 4 + wave;
      float4 a = *(const float4*)(x + (size_t)(tokbase + tok) * CDIM + c16 * 4);
      *(f16x4*)(&xl[(c16 >> 3) * PKKB + tok * 40 + (c16 & 7) * 4]) = pack4(a);
    }
  }
  __syncthreads();

  f32x4 acc[4][4];  // [m-tile][n-tile]
#pragma unroll
  for (int mt = 0; mt < 4; ++mt)
#pragma unroll
    for (int nt = 0; nt < 4; ++nt) acc[mt][nt] = (f32x4){0.f, 0.f, 0.f, 0.f};

#pragma unroll
  for (int kk = 0; kk < 8; ++kk) {
    f16x8 af[4];
#pragma unroll
    for (int mt = 0; mt < 4; ++mt)
      af[mt] = *(const f16x8*)(W + kk * 8192 + (wbase + mt * 16 + l16) * 32 +
                               quad * 8);
    f16x8 bf[4];
#pragma unroll
    for (int nt = 0; nt < 4; ++nt)
      bf[nt] = *(const f16x8*)(&xl[kk * PKKB + (nt * 16 + l16) * 40 + quad * 8]);
#pragma unroll
    for (int mt = 0; mt < 4; ++mt)
#pragma unroll
      for (int nt = 0; nt < 4; ++nt)
        acc[mt][nt] = __builtin_amdgcn_mfma_f32_16x16x32_f16(af[mt], bf[nt],
                                                             acc[mt][nt], 0, 0, 0);
  }

  // epilogue: bias -> per-head L2 norm (d spans 2 m-tiles x 4 quads) -> store
  const int bt = tokbase >> 10, l0 = tokbase & 1023;
#pragma unroll
  for (int hh = 0; hh < 2; ++hh) {
    const int h = wave * 2 + hh;
    const size_t hb = (size_t)(bt * HEADS + h) * (LSEQ * DHEAD);
    float4 b0 = *(const float4*)(bias + wbase + hh * 32 + quad * 4);
    float4 b1 = *(const float4*)(bias + wbase + hh * 32 + 16 + quad * 4);
#pragma unroll
    for (int nt = 0; nt < 4; ++nt) {
      f32x4 a0 = acc[hh * 2 + 0][nt];
      f32x4 a1 = acc[hh * 2 + 1][nt];
      float v0[4], v1[4];
      v0[0] = a0[0] + b0.x; v0[1] = a0[1] + b0.y;
      v0[2] = a0[2] + b0.z; v0[3] = a0[3] + b0.w;
      v1[0] = a1[0] + b1.x; v1[1] = a1[1] + b1.y;
      v1[2] = a1[2] + b1.z; v1[3] = a1[3] + b1.w;
      float ss = 0.f;
#pragma unroll
      for (int r = 0; r < 4; ++r) ss += v0[r] * v0[r] + v1[r] * v1[r];
      ss += __shfl_xor(ss, 16);
      ss += __shfl_xor(ss, 32);
      const float inv = scale / fmaxf(sqrtf(ss), 1e-12f);
      const int tok_l = l0 + nt * 16 + l16;
      if (!transposed) {
        f16x4 o0, o1;
#pragma unroll
        for (int r = 0; r < 4; ++r) {
          o0[r] = (f16)(v0[r] * inv);
          o1[r] = (f16)(v1[r] * inv);
        }
        *(f16x4*)(out + hb + (size_t)tok_l * DHEAD + quad * 4) = o0;
        *(f16x4*)(out + hb + (size_t)tok_l * DHEAD + 16 + quad * 4) = o1;
      } else {
        // column index with bits 2<->3 swapped (within each 16-token block):
        const int tcol = (tok_l & ~12) | ((tok_l & 4) << 1) | ((tok_l & 8) >> 1);
#pragma unroll
        for (int r = 0; r < 4; ++r) {
          out[hb + (size_t)(quad * 4 + r) * LSEQ + tcol] = (f16)(v0[r] * inv);
          out[hb + (size_t)(16 + quad * 4 + r) * LSEQ + tcol] = (f16)(v1[r] * inv);
        }
      }
    }
  }
}

// ---------------------------------------------------------------------------
// Kernel 2: attention via swapped 32x32x16 MFMA. Round 7: ONE barrier per
// k-tile. ds_write of tile t+1 moved to the top of iteration t: its previous
// readers (compute(t-1)) are fenced by the barrier at the end of iter t-1,
// and its consumers (compute(t+1)) are fenced by the barrier at the end of
// iter t. Loads for tile t+2 issue right after, hiding under compute(t).
// ---------------------------------------------------------------------------
#define TKROW 40  // padded K row, f16 units (64 rows/tile)
#define TVROW 72  // padded V row, f16 units (32 rows, 64 k-cols/tile)

__global__ __launch_bounds__(256, 4)
void attn_mfma_kernel(const f16* __restrict__ qn,
                      const f16* __restrict__ kn,
                      const f16* __restrict__ vt,
                      f16* __restrict__ xo) {
  __shared__ f16 kl[2][64 * TKROW];  // 2 x 5120B
  __shared__ f16 vl[2][32 * TVROW];  // 2 x 4608B
  const int tid  = threadIdx.x;
  const int wave = tid >> 6, lane = tid & 63;
  const int l32 = lane & 31, hi = lane >> 5;
  // XCD-aware swizzle: all 8 q-chunk blocks of a head land on one XCD's L2.
  const int wid = (blockIdx.x & 7) * 128 + (blockIdx.x >> 3);
  const int bth = wid >> 3;
  const int qbase = ((wid & 7) << 7) + wave * 32;
  const size_t hb = (size_t)bth * (LSEQ * DHEAD);

  const f16* qp = qn + hb + (size_t)(qbase + l32) * DHEAD + hi * 8;
  const f16x8 qf0 = *(const f16x8*)qp;
  const f16x8 qf1 = *(const f16x8*)(qp + 16);

  const int krow_w = wave * 16 + (lane >> 2), kcol = (lane & 3) * 8;
  const int vrow_w = wave * 8 + (lane >> 3), vcol = (lane & 7) * 8;
  const f16* gK = kn + hb + (size_t)krow_w * DHEAD + kcol;  // + t*64*DHEAD
  const f16* gV = vt + hb + (size_t)vrow_w * LSEQ + vcol;   // + t*64
  const int lK = krow_w * TKROW + kcol;
  const int lV = vrow_w * TVROW + vcol;

  f32x16 oacc, z16;
#pragma unroll
  for (int r = 0; r < 16; ++r) { oacc[r] = 0.f; z16[r] = 0.f; }
  float ls0 = 0.f, ls1 = 0.f;

#define EXPPV(s, v0, v1) { \
    union { f16x8 v; f16x2 h[4]; } _q0, _q1; \
    _Pragma("unroll") \
    for (int i = 0; i < 4; ++i) { \
      float e0 = __builtin_amdgcn_exp2f(s[2 * i]); \
      float e1 = __builtin_amdgcn_exp2f(s[2 * i + 1]); \
      ls0 += e0; ls1 += e1; \
      _q0.h[i] = pkcvt(e0, e1); \
      float e2 = __builtin_amdgcn_exp2f(s[8 + 2 * i]); \
      float e3 = __builtin_amdgcn_exp2f(s[9 + 2 * i]); \
      ls0 += e2; ls1 += e3; \
      _q1.h[i] = pkcvt(e2, e3); \
    } \
    oacc = __builtin_amdgcn_mfma_f32_32x32x16_f16(v0, _q0.v, oacc, 0, 0, 0); \
    oacc = __builtin_amdgcn_mfma_f32_32x32x16_f16(v1, _q1.v, oacc, 0, 0, 0); }

  // prologue: stage tile 0, issue tile 1 loads
  f16x8 gk = *(const f16x8*)gK;
  f16x8 gv = *(const f16x8*)gV;
  *(f16x8*)(&kl[0][lK]) = gk;
  *(f16x8*)(&vl[0][lV]) = gv;
  gk = *(const f16x8*)(gK + 64 * DHEAD);
  gv = *(const f16x8*)(gV + 64);
  __syncthreads();

  for (int t = 0; t < 16; ++t) {
    if (t < 15) {
      // write tile t+1 (old readers fenced by barrier at end of iter t-1)
      *(f16x8*)(&kl[(t + 1) & 1][lK]) = gk;
      *(f16x8*)(&vl[(t + 1) & 1][lV]) = gv;
      if (t < 14) {  // issue tile t+2 loads: covered by compute(t..t+1)
        gk = *(const f16x8*)(gK + (size_t)(t + 2) * 64 * DHEAD);
        gv = *(const f16x8*)(gV + (t + 2) * 64);
      }
    }
    const f16* kb = kl[t & 1];
    const f16* vb = vl[t & 1];
#pragma unroll
    for (int sub = 0; sub < 2; ++sub) {
      f16x8 kf0 = *(const f16x8*)(kb + (sub * 32 + l32) * TKROW + hi * 8);
      f16x8 kf1 = *(const f16x8*)(kb + (sub * 32 + l32) * TKROW + hi * 8 + 16);
      f16x8 vf0 = *(const f16x8*)(vb + l32 * TVROW + sub * 32 + hi * 8);
      f16x8 vf1 = *(const f16x8*)(vb + l32 * TVROW + sub * 32 + hi * 8 + 16);
      f32x16 s = __builtin_amdgcn_mfma_f32_32x32x16_f16(kf0, qf0, z16, 0, 0, 0);
      s = __builtin_amdgcn_mfma_f32_32x32x16_f16(kf1, qf1, s, 0, 0, 0);
      EXPPV(s, vf0, vf1)
    }
    __syncthreads();  // write(t+1) visible before compute(t+1); also fences
                      // next iteration's write of buf[t&1]
  }
#undef EXPPV

  float lsum = ls0 + ls1;        // own 16 k-rows
  lsum += __shfl_xor(lsum, 32);  // + partner half's 16 k-rows
  const float inv = __builtin_amdgcn_rcpf(lsum);

  f16* op = xo + hb + (size_t)(qbase + l32) * DHEAD + hi * 4;
#pragma unroll
  for (int g = 0; g < 4; ++g) {   // d-base = 8g + 4hi, 4 contiguous d each
    union { f16x4 v; f16x2 h[2]; } o;
    o.h[0] = pkcvt(oacc[4 * g + 0] * inv, oacc[4 * g + 1] * inv);
    o.h[1] = pkcvt(oacc[4 * g + 2] * inv, oacc[4 * g + 3] * inv);
    *(f16x4*)(op + 8 * g) = o.v;
  }
}

// ---------------------------------------------------------------------------
// Kernel 3: out = xatt @ Wm^T + bm + residual, f32 out, via MFMA.
// (unchanged from round 6 — dense k-major Wm16 A-frags + LDS-staged xatt.)
// ---------------------------------------------------------------------------
#define OKKB 1288  // (32 tok * 40 + 8 pad) f16 per head block

__global__ __launch_bounds__(256, 2)
void out_proj_mfma_kernel(const f16* __restrict__ xatt,
                          const f16* __restrict__ wm16,
                          const float* __restrict__ bm,
                          const float* __restrict__ resid,
                          float* __restrict__ out) {
  __shared__ f16 xl[8 * OKKB];  // 20608 B
  const int tid = threadIdx.x;
  const int wave = tid >> 6, lane = tid & 63;
  const int quad = lane >> 4, l16 = lane & 15;
  const int tokbase = blockIdx.x * 32;
  const int wbase = wave * 64;
  const int bt = tokbase >> 10, l0 = tokbase & 1023;

  {
#pragma unroll
    for (int r = 0; r < 4; ++r) {
      const int flat = r * 256 + tid;           // kk*128 + tok*4 + c8
      const int kk = flat >> 7, rem = flat & 127;
      const int tok = rem >> 2, c8 = rem & 3;
      const f16* gp = xatt + (size_t)(bt * HEADS + kk) * (LSEQ * DHEAD) +
                      (size_t)(l0 + tok) * DHEAD + c8 * 8;
      *(f16x8*)(&xl[kk * OKKB + tok * 40 + c8 * 8]) = *(const f16x8*)gp;
    }
  }
  __syncthreads();

  f32x4 acc[4][2];
#pragma unroll
  for (int mt = 0; mt < 4; ++mt)
#pragma unroll
    for (int nt = 0; nt < 2; ++nt) acc[mt][nt] = (f32x4){0.f, 0.f, 0.f, 0.f};

#pragma unroll
  for (int kk = 0; kk < 8; ++kk) {
    f16x8 af[4];
#pragma unroll
    for (int mt = 0; mt < 4; ++mt)
      af[mt] = *(const f16x8*)(wm16 + kk * 8192 +
                               (wbase + mt * 16 + l16) * 32 + quad * 8);
    f16x8 bf0 = *(const f16x8*)(&xl[kk * OKKB + l16 * 40 + quad * 8]);
    f16x8 bf1 = *(const f16x8*)(&xl[kk * OKKB + (16 + l16) * 40 + quad * 8]);
#pragma unroll
    for (int mt = 0; mt < 4; ++mt) {
      acc[mt][0] = __builtin_amdgcn_mfma_f32_16x16x32_f16(af[mt], bf0,
                                                          acc[mt][0], 0, 0, 0);
      acc[mt][1] = __builtin_amdgcn_mfma_f32_16x16x32_f16(af[mt], bf1,
                                                          acc[mt][1], 0, 0, 0);
    }
  }

#pragma unroll
  for (int mt = 0; mt < 4; ++mt) {
    float4 bv = *(const float4*)(bm + wbase + mt * 16 + quad * 4);
#pragma unroll
    for (int nt = 0; nt < 2; ++nt) {
      const int tok = tokbase + nt * 16 + l16;
      const size_t off = (size_t)tok * CDIM + wbase + mt * 16 + quad * 4;
      float4 rv = *(const float4*)(resid + off);
      float4 o;
      o.x = acc[mt][nt][0] + bv.x + rv.x;
      o.y = acc[mt][nt][1] + bv.y + rv.y;
      o.z = acc[mt][nt][2] + bv.z + rv.z;
      o.w = acc[mt][nt][3] + bv.w + rv.w;
      *(float4*)(out + off) = o;
    }
  }
}

extern "C" void kernel_launch(void* const* d_in, const int* in_sizes, int n_in,
                              void* d_out, int out_size, void* d_ws,
                              size_t ws_size, hipStream_t stream) {
  const float* q  = (const float*)d_in[0];
  const float* k  = (const float*)d_in[1];
  const float* v  = (const float*)d_in[2];
  const float* Wq = (const float*)d_in[3];
  const float* bq = (const float*)d_in[4];
  const float* Wk = (const float*)d_in[5];
  const float* bk = (const float*)d_in[6];
  const float* Wv = (const float*)d_in[7];
  const float* bv = (const float*)d_in[8];
  const float* Wm = (const float*)d_in[9];
  const float* bm = (const float*)d_in[10];
  float* outp = (float*)d_out;

  f16* ws = (f16*)d_ws;
  const size_t TENS = (size_t)NTOK * CDIM;  // 4194304
  f16* qn  = ws;
  f16* kn  = ws + TENS;
  f16* vt  = ws + 2 * TENS;
  f16* w16 = ws + 3 * TENS;  // 4 x 65536 f16 (Wq,Wk,Wv,Wm k-major tiles)
  f16* xa  = qn;             // alias: attn reads its q-rows before writing

  dim3 blk(256);
  cvt_w_kernel<<<dim3(256), blk, 0, stream>>>(Wq, Wk, Wv, Wm, w16);
  proj_mfma_kernel<<<dim3(256, 3), blk, 0, stream>>>(q, k, v, w16, bq, bk, bv,
                                                     qn, kn, vt);
  attn_mfma_kernel<<<dim3(1024), blk, 0, stream>>>(qn, kn, vt, xa);
  out_proj_mfma_kernel<<<dim3(512), blk, 0, stream>>>(xa, w16 + 3 * 65536, bm,
                                                      q, outp);
}

// Round 8
// 154.501 us; speedup vs baseline: 1.0326x; 1.0326x over previous
//
#include <hip/hip_runtime.h>
#include <hip/hip_bf16.h>

// Shapes: b=2,t=8,l=1024,c=256,h=8,d=32 -> NTOK=16384, BTH=128
// Inputs/outputs: float32. ws intermediates: _Float16.
// ws layout (f16): qn | kn | vt (each 4194304 elems, 24MB) | w16 (4x65536,
//   512KB, k-major tiled [kk][och][32] for Wq,Wk,Wv,Wm).
//   xa ALIASES qn (attn reads its q-rows before writing them; disjoint
//   across blocks). vt TRANSPOSED [bth][32][l], k-index bits 2<->3 swapped
//   within each 16-block so a plain f16x8 load is the PV A-fragment.
// qn pre-scaled by log2(e)/sqrt(32) so attn uses exp2 directly.
//
// Round 8: attn KTILE 64->128. Mechanism: the compiler emits
// s_waitcnt vmcnt(0) before every s_barrier, draining prefetch regs at each
// sync point; fewer+bigger tiles halve the drains (7 vs 15) and double the
// compute covering each prefetch. + s_setprio(1) around the MFMA/softmax
// cluster (T5). proj reverted to the round-6 measured-best config.

#define NTOK  16384
#define CDIM  256
#define LSEQ  1024
#define HEADS 8
#define DHEAD 32

typedef _Float16 f16;
typedef __attribute__((ext_vector_type(2))) _Float16 f16x2;
typedef __attribute__((ext_vector_type(4))) _Float16 f16x4;
typedef __attribute__((ext_vector_type(8))) _Float16 f16x8;
typedef __attribute__((ext_vector_type(4))) float f32x4;
typedef __attribute__((ext_vector_type(16))) float f32x16;

#define QSCALE (0.17677669529663687f * 1.4426950408889634f)  // 1/sqrt(32)*log2e

__device__ __forceinline__ f16x2 pkcvt(float a, float b) {
  auto r = __builtin_amdgcn_cvt_pkrtz(a, b);  // v_cvt_pkrtz_f16_f32
  union { decltype(r) in; f16x2 out; } u;
  u.in = r;
  return u.out;
}

__device__ __forceinline__ f16x4 pack4(float4 a) {
  union { f16x4 v; f16x2 h[2]; } u;
  u.h[0] = pkcvt(a.x, a.y);
  u.h[1] = pkcvt(a.z, a.w);
  return u.v;
}

// ---------------------------------------------------------------------------
// Kernel 0: convert Wq|Wk|Wv|Wm (each 256x256 f32) to f16 in k-major tiles:
// dst[m*65536 + kk*8192 + och*32 + (ch&31)] — a wave's MFMA A-fragment load
// (16 och rows x 32 ch) is one contiguous 1KB block.
// ---------------------------------------------------------------------------
__global__ __launch_bounds__(256)
void cvt_w_kernel(const float* __restrict__ Wq, const float* __restrict__ Wk,
                  const float* __restrict__ Wv, const float* __restrict__ Wm,
                  f16* __restrict__ dst) {
  const int m = blockIdx.x >> 6;  // matrix index (4 x 64 blocks)
  const float* src = (m == 0) ? Wq : (m == 1) ? Wk : (m == 2) ? Wv : Wm;
  const int base = (blockIdx.x & 63) * 1024 + threadIdx.x * 4;  // och*256+ch
  const int och = base >> 8, ch = base & 255;
  float4 a = *(const float4*)(src + base);
  *(f16x4*)(dst + m * 65536 + (ch >> 5) * 8192 + och * 32 + (ch & 31)) =
      pack4(a);
}

// ---------------------------------------------------------------------------
// Kernel 1: fused Q/K/V projection + bias + per-head L2-norm via MFMA.
// (exact round-6 config — measured best: 32 tokens/block, grid (512,3).)
// x tile staged to LDS [kk][tok][40] via dense 1KB token-row reads + pkcvt;
// A-frags from k-major w16 (dense 1KB). No strided hot loads.
// ---------------------------------------------------------------------------
#define PKKB 1288  // (32 tok * 40 + 8 pad) f16 per kk block

__global__ __launch_bounds__(256, 2)
void proj_mfma_kernel(const float* __restrict__ xq, const float* __restrict__ xk,
                      const float* __restrict__ xv, const f16* __restrict__ w16,
                      const float* __restrict__ bq, const float* __restrict__ bk,
                      const float* __restrict__ bv,
                      f16* __restrict__ qn, f16* __restrict__ kn,
                      f16* __restrict__ vt) {
  __shared__ f16 xl[8 * PKKB];  // 20608 B
  const int which = blockIdx.y;
  const float* x    = (which == 0) ? xq : (which == 1) ? xk : xv;
  const float* bias = (which == 0) ? bq : (which == 1) ? bk : bv;
  const f16* W      = w16 + which * 65536;
  f16* out          = (which == 0) ? qn : (which == 1) ? kn : vt;
  const float scale = (which == 0) ? QSCALE : 1.0f;
  const bool transposed = (which == 2);

  const int tid = threadIdx.x;
  const int wave = tid >> 6, lane = tid & 63;
  const int quad = lane >> 4, l16 = lane & 15;
  const int tokbase = blockIdx.x * 32;
  const int wbase = wave * 64;

  // stage x tile: 8 rounds, each wave reads ONE full token row (1KB dense).
  {
    const int c16 = lane;  // 64 16B-chunks per token
#pragma unroll
    for (int r = 0; r < 8; ++r) {
      const int tok = r * 4 + wave;
      float4 a = *(const float4*)(x + (size_t)(tokbase + tok) * CDIM + c16 * 4);
      *(f16x4*)(&xl[(c16 >> 3) * PKKB + tok * 40 + (c16 & 7) * 4]) = pack4(a);
    }
  }
  __syncthreads();

  f32x4 acc[4][2];  // [m-tile][n-tile]
#pragma unroll
  for (int mt = 0; mt < 4; ++mt)
#pragma unroll
    for (int nt = 0; nt < 2; ++nt) acc[mt][nt] = (f32x4){0.f, 0.f, 0.f, 0.f};

#pragma unroll
  for (int kk = 0; kk < 8; ++kk) {
    f16x8 af[4];
#pragma unroll
    for (int mt = 0; mt < 4; ++mt)
      af[mt] = *(const f16x8*)(W + kk * 8192 + (wbase + mt * 16 + l16) * 32 +
                               quad * 8);
    f16x8 bf0 = *(const f16x8*)(&xl[kk * PKKB + l16 * 40 + quad * 8]);
    f16x8 bf1 = *(const f16x8*)(&xl[kk * PKKB + (16 + l16) * 40 + quad * 8]);
#pragma unroll
    for (int mt = 0; mt < 4; ++mt) {
      acc[mt][0] = __builtin_amdgcn_mfma_f32_16x16x32_f16(af[mt], bf0,
                                                          acc[mt][0], 0, 0, 0);
      acc[mt][1] = __builtin_amdgcn_mfma_f32_16x16x32_f16(af[mt], bf1,
                                                          acc[mt][1], 0, 0, 0);
    }
  }

  // epilogue: bias -> per-head L2 norm -> store
  const int bt = tokbase >> 10, l0 = tokbase & 1023;
#pragma unroll
  for (int hh = 0; hh < 2; ++hh) {
    const int h = wave * 2 + hh;
    const size_t hb = (size_t)(bt * HEADS + h) * (LSEQ * DHEAD);
    float4 b0 = *(const float4*)(bias + wbase + hh * 32 + quad * 4);
    float4 b1 = *(const float4*)(bias + wbase + hh * 32 + 16 + quad * 4);
#pragma unroll
    for (int nt = 0; nt < 2; ++nt) {
      f32x4 a0 = acc[hh * 2 + 0][nt];
      f32x4 a1 = acc[hh * 2 + 1][nt];
      float v0[4], v1[4];
      v0[0] = a0[0] + b0.x; v0[1] = a0[1] + b0.y;
      v0[2] = a0[2] + b0.z; v0[3] = a0[3] + b0.w;
      v1[0] = a1[0] + b1.x; v1[1] = a1[1] + b1.y;
      v1[2] = a1[2] + b1.z; v1[3] = a1[3] + b1.w;
      float ss = 0.f;
#pragma unroll
      for (int r = 0; r < 4; ++r) ss += v0[r] * v0[r] + v1[r] * v1[r];
      ss += __shfl_xor(ss, 16);
      ss += __shfl_xor(ss, 32);
      const float inv = scale / fmaxf(sqrtf(ss), 1e-12f);
      const int tok_l = l0 + nt * 16 + l16;
      if (!transposed) {
        f16x4 o0, o1;
#pragma unroll
        for (int r = 0; r < 4; ++r) {
          o0[r] = (f16)(v0[r] * inv);
          o1[r] = (f16)(v1[r] * inv);
        }
        *(f16x4*)(out + hb + (size_t)tok_l * DHEAD + quad * 4) = o0;
        *(f16x4*)(out + hb + (size_t)tok_l * DHEAD + 16 + quad * 4) = o1;
      } else {
        const int tcol = (tok_l & ~12) | ((tok_l & 4) << 1) | ((tok_l & 8) >> 1);
#pragma unroll
        for (int r = 0; r < 4; ++r) {
          out[hb + (size_t)(quad * 4 + r) * LSEQ + tcol] = (f16)(v0[r] * inv);
          out[hb + (size_t)(16 + quad * 4 + r) * LSEQ + tcol] = (f16)(v1[r] * inv);
        }
      }
    }
  }
}

// ---------------------------------------------------------------------------
// Kernel 2: attention via swapped 32x32x16 MFMA. Round 8: KTILE=128 (8
// k-iterations, round-4's verified two-barrier shape -> 14 sync-drains vs
// 31), register prefetch of tile t+2 covered by a full 128-row compute
// phase; s_setprio(1) around the MFMA/softmax cluster.
// ---------------------------------------------------------------------------
#define TKROW 40   // padded K row (80B), 128 rows/tile
#define TVROW 136  // padded V row: 128 k-cols + 8 pad (272B), 32 d-rows

__global__ __launch_bounds__(256, 4)
void attn_mfma_kernel(const f16* __restrict__ qn,
                      const f16* __restrict__ kn,
                      const f16* __restrict__ vt,
                      f16* __restrict__ xo) {
  __shared__ f16 kl[2][128 * TKROW];  // 2 x 10240B
  __shared__ f16 vl[2][32 * TVROW];   // 2 x 8704B
  const int tid  = threadIdx.x;
  const int wave = tid >> 6, lane = tid & 63;
  const int l32 = lane & 31, hi = lane >> 5;
  // XCD-aware swizzle: all 8 q-chunk blocks of a head land on one XCD's L2.
  const int wid = (blockIdx.x & 7) * 128 + (blockIdx.x >> 3);
  const int bth = wid >> 3;
  const int qbase = ((wid & 7) << 7) + wave * 32;
  const size_t hb = (size_t)bth * (LSEQ * DHEAD);

  const f16* qp = qn + hb + (size_t)(qbase + l32) * DHEAD + hi * 8;
  const f16x8 qf0 = *(const f16x8*)qp;
  const f16x8 qf1 = *(const f16x8*)(qp + 16);

  // K staging: wave stages rows wave*32..+31 (2KB dense). lane: row =
  // wave*32 + (lane>>1), 32B-half = lane&1 -> two f16x8 writes.
  const int krow_w = wave * 32 + (lane >> 1), kc0 = (lane & 1) * 16;
  const f16* gKb = kn + hb + (size_t)krow_w * DHEAD + kc0;  // + t*128*DHEAD
  const int lK = krow_w * TKROW + kc0;
  // V staging: wave stages d-rows wave*8..+7, chunks (lane&7) and +8 of 16.
  const int vrow_w = wave * 8 + (lane >> 3), vc0 = (lane & 7) * 8;
  const f16* gVb = vt + hb + (size_t)vrow_w * LSEQ + vc0;   // + t*128
  const int lV = vrow_w * TVROW + vc0;

  f32x16 oacc, z16;
#pragma unroll
  for (int r = 0; r < 16; ++r) { oacc[r] = 0.f; z16[r] = 0.f; }
  float ls0 = 0.f, ls1 = 0.f;

#define EXPPV(s, v0, v1) { \
    union { f16x8 v; f16x2 h[4]; } _q0, _q1; \
    _Pragma("unroll") \
    for (int i = 0; i < 4; ++i) { \
      float e0 = __builtin_amdgcn_exp2f(s[2 * i]); \
      float e1 = __builtin_amdgcn_exp2f(s[2 * i + 1]); \
      ls0 += e0; ls1 += e1; \
      _q0.h[i] = pkcvt(e0, e1); \
      float e2 = __builtin_amdgcn_exp2f(s[8 + 2 * i]); \
      float e3 = __builtin_amdgcn_exp2f(s[9 + 2 * i]); \
      ls0 += e2; ls1 += e3; \
      _q1.h[i] = pkcvt(e2, e3); \
    } \
    oacc = __builtin_amdgcn_mfma_f32_32x32x16_f16(v0, _q0.v, oacc, 0, 0, 0); \
    oacc = __builtin_amdgcn_mfma_f32_32x32x16_f16(v1, _q1.v, oacc, 0, 0, 0); }

  // prologue: stage tile 0, prefetch tile 1 into regs
  f16x8 gk0 = *(const f16x8*)gKb;
  f16x8 gk1 = *(const f16x8*)(gKb + 8);
  f16x8 gv0 = *(const f16x8*)gVb;
  f16x8 gv1 = *(const f16x8*)(gVb + 64);
  *(f16x8*)(&kl[0][lK])      = gk0;
  *(f16x8*)(&kl[0][lK + 8])  = gk1;
  *(f16x8*)(&vl[0][lV])      = gv0;
  *(f16x8*)(&vl[0][lV + 64]) = gv1;
  gk0 = *(const f16x8*)(gKb + 128 * DHEAD);
  gk1 = *(const f16x8*)(gKb + 128 * DHEAD + 8);
  gv0 = *(const f16x8*)(gVb + 128);
  gv1 = *(const f16x8*)(gVb + 128 + 64);
  __syncthreads();

  for (int t = 0; t < 8; ++t) {
    const f16* kb = kl[t & 1];
    const f16* vb = vl[t & 1];
    __builtin_amdgcn_s_setprio(1);
#pragma unroll
    for (int sub = 0; sub < 4; ++sub) {
      f16x8 kf0 = *(const f16x8*)(kb + (sub * 32 + l32) * TKROW + hi * 8);
      f16x8 kf1 = *(const f16x8*)(kb + (sub * 32 + l32) * TKROW + hi * 8 + 16);
      f16x8 vf0 = *(const f16x8*)(vb + l32 * TVROW + sub * 32 + hi * 8);
      f16x8 vf1 = *(const f16x8*)(vb + l32 * TVROW + sub * 32 + hi * 8 + 16);
      f32x16 s = __builtin_amdgcn_mfma_f32_32x32x16_f16(kf0, qf0, z16, 0, 0, 0);
      s = __builtin_amdgcn_mfma_f32_32x32x16_f16(kf1, qf1, s, 0, 0, 0);
      EXPPV(s, vf0, vf1)
    }
    __builtin_amdgcn_s_setprio(0);
    if (t < 7) {
      __syncthreads();  // all waves done reading buf[(t+1)&1] (tile t-1)
      *(f16x8*)(&kl[(t + 1) & 1][lK])      = gk0;
      *(f16x8*)(&kl[(t + 1) & 1][lK + 8])  = gk1;
      *(f16x8*)(&vl[(t + 1) & 1][lV])      = gv0;
      *(f16x8*)(&vl[(t + 1) & 1][lV + 64]) = gv1;
      if (t < 6) {  // prefetch tile t+2: covered by a full 128-row compute
        gk0 = *(const f16x8*)(gKb + (size_t)(t + 2) * 128 * DHEAD);
        gk1 = *(const f16x8*)(gKb + (size_t)(t + 2) * 128 * DHEAD + 8);
        gv0 = *(const f16x8*)(gVb + (t + 2) * 128);
        gv1 = *(const f16x8*)(gVb + (t + 2) * 128 + 64);
      }
      __syncthreads();  // buf[(t+1)&1] visible
    }
  }
#undef EXPPV

  float lsum = ls0 + ls1;        // own 16 k-rows
  lsum += __shfl_xor(lsum, 32);  // + partner half's 16 k-rows
  const float inv = __builtin_amdgcn_rcpf(lsum);

  f16* op = xo + hb + (size_t)(qbase + l32) * DHEAD + hi * 4;
#pragma unroll
  for (int g = 0; g < 4; ++g) {   // d-base = 8g + 4hi, 4 contiguous d each
    union { f16x4 v; f16x2 h[2]; } o;
    o.h[0] = pkcvt(oacc[4 * g + 0] * inv, oacc[4 * g + 1] * inv);
    o.h[1] = pkcvt(oacc[4 * g + 2] * inv, oacc[4 * g + 3] * inv);
    *(f16x4*)(op + 8 * g) = o.v;
  }
}

// ---------------------------------------------------------------------------
// Kernel 3: out = xatt @ Wm^T + bm + residual, f32 out, via MFMA.
// (unchanged from round 6 — dense k-major Wm16 A-frags + LDS-staged xatt.)
// ---------------------------------------------------------------------------
#define OKKB 1288  // (32 tok * 40 + 8 pad) f16 per head block

__global__ __launch_bounds__(256, 2)
void out_proj_mfma_kernel(const f16* __restrict__ xatt,
                          const f16* __restrict__ wm16,
                          const float* __restrict__ bm,
                          const float* __restrict__ resid,
                          float* __restrict__ out) {
  __shared__ f16 xl[8 * OKKB];  // 20608 B
  const int tid = threadIdx.x;
  const int wave = tid >> 6, lane = tid & 63;
  const int quad = lane >> 4, l16 = lane & 15;
  const int tokbase = blockIdx.x * 32;
  const int wbase = wave * 64;
  const int bt = tokbase >> 10, l0 = tokbase & 1023;

  {
#pragma unroll
    for (int r = 0; r < 4; ++r) {
      const int flat = r * 256 + tid;           // kk*128 + tok*4 + c8
      const int kk = flat >> 7, rem = flat & 127;
      const int tok = rem >> 2, c8 = rem & 3;
      const f16* gp = xatt + (size_t)(bt * HEADS + kk) * (LSEQ * DHEAD) +
                      (size_t)(l0 + tok) * DHEAD + c8 * 8;
      *(f16x8*)(&xl[kk * OKKB + tok * 40 + c8 * 8]) = *(const f16x8*)gp;
    }
  }
  __syncthreads();

  f32x4 acc[4][2];
#pragma unroll
  for (int mt = 0; mt < 4; ++mt)
#pragma unroll
    for (int nt = 0; nt < 2; ++nt) acc[mt][nt] = (f32x4){0.f, 0.f, 0.f, 0.f};

#pragma unroll
  for (int kk = 0; kk < 8; ++kk) {
    f16x8 af[4];
#pragma unroll
    for (int mt = 0; mt < 4; ++mt)
      af[mt] = *(const f16x8*)(wm16 + kk * 8192 +
                               (wbase + mt * 16 + l16) * 32 + quad * 8);
    f16x8 bf0 = *(const f16x8*)(&xl[kk * OKKB + l16 * 40 + quad * 8]);
    f16x8 bf1 = *(const f16x8*)(&xl[kk * OKKB + (16 + l16) * 40 + quad * 8]);
#pragma unroll
    for (int mt = 0; mt < 4; ++mt) {
      acc[mt][0] = __builtin_amdgcn_mfma_f32_16x16x32_f16(af[mt], bf0,
                                                          acc[mt][0], 0, 0, 0);
      acc[mt][1] = __builtin_amdgcn_mfma_f32_16x16x32_f16(af[mt], bf1,
                                                          acc[mt][1], 0, 0, 0);
    }
  }

#pragma unroll
  for (int mt = 0; mt < 4; ++mt) {
    float4 bv = *(const float4*)(bm + wbase + mt * 16 + quad * 4);
#pragma unroll
    for (int nt = 0; nt < 2; ++nt) {
      const int tok = tokbase + nt * 16 + l16;
      const size_t off = (size_t)tok * CDIM + wbase + mt * 16 + quad * 4;
      float4 rv = *(const float4*)(resid + off);
      float4 o;
      o.x = acc[mt][nt][0] + bv.x + rv.x;
      o.y = acc[mt][nt][1] + bv.y + rv.y;
      o.z = acc[mt][nt][2] + bv.z + rv.z;
      o.w = acc[mt][nt][3] + bv.w + rv.w;
      *(float4*)(out + off) = o;
    }
  }
}

extern "C" void kernel_launch(void* const* d_in, const int* in_sizes, int n_in,
                              void* d_out, int out_size, void* d_ws,
                              size_t ws_size, hipStream_t stream) {
  const float* q  = (const float*)d_in[0];
  const float* k  = (const float*)d_in[1];
  const float* v  = (const float*)d_in[2];
  const float* Wq = (const float*)d_in[3];
  const float* bq = (const float*)d_in[4];
  const float* Wk = (const float*)d_in[5];
  const float* bk = (const float*)d_in[6];
  const float* Wv = (const float*)d_in[7];
  const float* bv = (const float*)d_in[8];
  const float* Wm = (const float*)d_in[9];
  const float* bm = (const float*)d_in[10];
  float* outp = (float*)d_out;

  f16* ws = (f16*)d_ws;
  const size_t TENS = (size_t)NTOK * CDIM;  // 4194304
  f16* qn  = ws;
  f16* kn  = ws + TENS;
  f16* vt  = ws + 2 * TENS;
  f16* w16 = ws + 3 * TENS;  // 4 x 65536 f16 (Wq,Wk,Wv,Wm k-major tiles)
  f16* xa  = qn;             // alias: attn reads its q-rows before writing

  dim3 blk(256);
  cvt_w_kernel<<<dim3(256), blk, 0, stream>>>(Wq, Wk, Wv, Wm, w16);
  proj_mfma_kernel<<<dim3(512, 3), blk, 0, stream>>>(q, k, v, w16, bq, bk, bv,
                                                     qn, kn, vt);
  attn_mfma_kernel<<<dim3(1024), blk, 0, stream>>>(qn, kn, vt, xa);
  out_proj_mfma_kernel<<<dim3(512), blk, 0, stream>>>(xa, w16 + 3 * 65536, bm,
                                                      q, outp);
}